// Round 1
// baseline (6681.158 us; speedup 1.0000x reference)
//
#include <hip/hip_runtime.h>
#include <hip/hip_bf16.h>
#include <math.h>

#define B_ 32
#define L_ 128
#define E_ 300
#define H_ 512
#define DOUT_ 5
#define NSTEP 5
#define CTXK 2348   // 3H + E + H
#define G7 3584     // 7H

// ---------------- helpers ----------------
__global__ void fill_zero(float* __restrict__ p, int n) {
  int i = blockIdx.x * blockDim.x + threadIdx.x;
  if (i < n) p[i] = 0.f;
}

__global__ void mask_lens_kernel(const int* __restrict__ lengths,
                                 float* __restrict__ maskf,
                                 float* __restrict__ invlens) {
  int i = blockIdx.x * blockDim.x + threadIdx.x;  // over B*L
  if (i < B_ * L_) {
    int b = i >> 7, l = i & 127;
    maskf[i] = (l < lengths[b]) ? 1.f : 0.f;
    if (l == 0) {
      float le = (float)lengths[b];
      invlens[b] = 1.f / fmaxf(le, 1.f);
    }
  }
}

__global__ void embed_kernel(const int* __restrict__ tokens,
                             const float* __restrict__ embed,
                             float* __restrict__ x) {
  int i = blockIdx.x * blockDim.x + threadIdx.x;  // over B*L*E
  if (i < B_ * L_ * E_) {
    int e = i % E_;
    int bl = i / E_;
    x[i] = embed[(size_t)tokens[bl] * E_ + e];
  }
}

// ---------------- generic fp32 tiled GEMM: C = A[M,K] @ B[K,N] + bias ----------------
// act: 0 = none, 1 = tanh. rowscale: optional per-row multiplier (applied last).
// Requires M % 64 == 0 and N % 64 == 0 (true for all call sites). K arbitrary.
__global__ __launch_bounds__(256) void gemm_bias(
    const float* __restrict__ A, const float* __restrict__ Bm,
    const float* __restrict__ bias, const float* __restrict__ rowscale,
    float* __restrict__ C, int M, int N, int K, int act) {
  __shared__ __align__(16) float As[16][68];  // [kk][row], padded
  __shared__ __align__(16) float Bs[16][64];  // [kk][col]
  const int tx = threadIdx.x, ty = threadIdx.y;
  const int tid = ty * 16 + tx;
  const int rowBase = blockIdx.y * 64;
  const int colBase = blockIdx.x * 64;
  float acc[4][4] = {{0.f}};
  const int numT = (K + 15) >> 4;
  for (int t = 0; t < numT; ++t) {
    const int k0 = t << 4;
#pragma unroll
    for (int i = 0; i < 4; ++i) {
      int lin = tid + i * 256;
      int r = lin >> 4, cc = lin & 15;
      int gk = k0 + cc;
      As[cc][r] = (gk < K) ? A[(size_t)(rowBase + r) * K + gk] : 0.f;
    }
#pragma unroll
    for (int i = 0; i < 4; ++i) {
      int lin = tid + i * 256;
      int r = lin >> 6, cc = lin & 63;
      int gk = k0 + r;
      Bs[r][cc] = (gk < K) ? Bm[(size_t)gk * N + colBase + cc] : 0.f;
    }
    __syncthreads();
#pragma unroll
    for (int kk = 0; kk < 16; ++kk) {
      float4 a4 = *(const float4*)&As[kk][ty * 4];
      float4 b4 = *(const float4*)&Bs[kk][tx * 4];
      float av[4] = {a4.x, a4.y, a4.z, a4.w};
      float bv[4] = {b4.x, b4.y, b4.z, b4.w};
#pragma unroll
      for (int i = 0; i < 4; ++i)
#pragma unroll
        for (int j = 0; j < 4; ++j)
          acc[i][j] = fmaf(av[i], bv[j], acc[i][j]);
    }
    __syncthreads();
  }
#pragma unroll
  for (int i = 0; i < 4; ++i) {
    int row = rowBase + ty * 4 + i;
    float rs = rowscale ? rowscale[row] : 1.f;
#pragma unroll
    for (int j = 0; j < 4; ++j) {
      int col = colBase + tx * 4 + j;
      float v = acc[i][j] + bias[col];
      if (act == 1) v = tanhf(v);
      v *= rs;
      C[(size_t)row * N + col] = v;
    }
  }
}

// ---------------- per-step kernels ----------------
__global__ void build_ctx_kernel(const float* __restrict__ h,
                                 const float* __restrict__ x,
                                 const float* __restrict__ g,
                                 float* __restrict__ ctx) {
  int k = blockIdx.x * blockDim.x + threadIdx.x;
  int bl = blockIdx.y;
  if (k >= CTXK) return;
  int b = bl >> 7, l = bl & 127;
  float v;
  if (k < H_) {
    v = (l >= 1) ? h[(size_t)(bl - 1) * H_ + k] : 0.f;
  } else if (k < 2 * H_) {
    v = h[(size_t)bl * H_ + (k - H_)];
  } else if (k < 3 * H_) {
    v = (l < L_ - 1) ? h[(size_t)(bl + 1) * H_ + (k - 2 * H_)] : 0.f;
  } else if (k < 3 * H_ + E_) {
    v = x[(size_t)bl * E_ + (k - 3 * H_)];
  } else {
    v = g[(size_t)b * H_ + (k - 3 * H_ - E_)];
  }
  ctx[(size_t)bl * CTXK + k] = v;
}

__global__ void cell_update_kernel(const float* __restrict__ gates,
                                   const float* __restrict__ c_old,
                                   const float* __restrict__ cg_old,
                                   const float* __restrict__ maskf,
                                   float* __restrict__ h_new,
                                   float* __restrict__ c_new) {
  int idx = blockIdx.x * blockDim.x + threadIdx.x;  // B*L*H
  if (idx >= B_ * L_ * H_) return;
  int hh = idx & (H_ - 1);
  int bl = idx >> 9;
  int b = bl >> 7, l = bl & 127;
  const float* gr_ = gates + (size_t)bl * G7;
  float gi = gr_[hh], gl = gr_[H_ + hh], gf = gr_[2 * H_ + hh],
        grr = gr_[3 * H_ + hh], gs = gr_[4 * H_ + hh],
        go = gr_[5 * H_ + hh], gu = gr_[6 * H_ + hh];
  float m = fmaxf(fmaxf(fmaxf(gi, gl), fmaxf(gf, grr)), gs);
  float ei = expf(gi - m), el = expf(gl - m), ef = expf(gf - m),
        er = expf(grr - m), es = expf(gs - m);
  float inv = 1.f / (ei + el + ef + er + es);
  float o = 1.f / (1.f + expf(-go));
  float u = tanhf(gu);
  float cprev = (l >= 1) ? c_old[idx - H_] : 0.f;
  float ccur = c_old[idx];
  float cnext = (l < L_ - 1) ? c_old[idx + H_] : 0.f;
  float cgv = cg_old[b * H_ + hh];
  float mk = maskf[bl];
  float cn = (el * cprev + ef * ccur + er * cnext + es * cgv + ei * u) * inv * mk;
  float hn = o * tanhf(cn) * mk;
  c_new[idx] = cn;
  h_new[idx] = hn;
}

__global__ void reduce_mean_kernel(const float* __restrict__ hin,
                                   const float* __restrict__ invlens,
                                   float* __restrict__ out) {
  int i = blockIdx.x * blockDim.x + threadIdx.x;  // B*H
  if (i >= B_ * H_) return;
  int b = i >> 9;
  const float* p = hin + (size_t)b * L_ * H_ + (i & (H_ - 1));
  float s = 0.f;
#pragma unroll 4
  for (int l = 0; l < L_; ++l) s += p[(size_t)l * H_];
  out[i] = s * invlens[b];
}

__global__ void gnode_kernel(const float* __restrict__ g,
                             const float* __restrict__ havg,
                             const float* __restrict__ Wgf,
                             const float* __restrict__ bgf,
                             const float* __restrict__ Wgo,
                             const float* __restrict__ bgo,
                             float* __restrict__ fg, float* __restrict__ og) {
  int i = blockIdx.x * blockDim.x + threadIdx.x;  // B*H
  if (i >= B_ * H_) return;
  int b = i >> 9, hh = i & (H_ - 1);
  float af = bgf[hh], ao = bgo[hh];
  const float* grow = g + b * H_;
  const float* hrow = havg + b * H_;
  for (int k = 0; k < H_; ++k) {
    float gv = grow[k];
    af = fmaf(gv, Wgf[(size_t)k * H_ + hh], af);
    ao = fmaf(gv, Wgo[(size_t)k * H_ + hh], ao);
  }
  for (int k = 0; k < H_; ++k) {
    float hv = hrow[k];
    af = fmaf(hv, Wgf[(size_t)(H_ + k) * H_ + hh], af);
    ao = fmaf(hv, Wgo[(size_t)(H_ + k) * H_ + hh], ao);
  }
  fg[i] = af;
  og[i] = 1.f / (1.f + expf(-ao));
}

__global__ void build_ficat_kernel(const float* __restrict__ g,
                                   const float* __restrict__ h_new,
                                   float* __restrict__ ficat) {
  int k = blockIdx.x * blockDim.x + threadIdx.x;  // 0..1023
  int bl = blockIdx.y;
  if (k >= 2 * H_) return;
  int b = bl >> 7;
  float v = (k < H_) ? g[b * H_ + k] : h_new[(size_t)bl * H_ + (k - H_)];
  ficat[(size_t)bl * (2 * H_) + k] = v;
}

// online softmax over L+1 slots per (b,h); slot0 logit=fg value=cg_old,
// slots 1..L logit=fi[l] value=c_new[l] (only where mask>0).
__global__ void slot_update_kernel(const float* __restrict__ fg,
                                   const float* __restrict__ fi,
                                   const float* __restrict__ og,
                                   const float* __restrict__ c_new,
                                   const float* __restrict__ cg_old,
                                   const float* __restrict__ maskf,
                                   float* __restrict__ cg_new,
                                   float* __restrict__ g_new) {
  int i = blockIdx.x * blockDim.x + threadIdx.x;  // B*H
  if (i >= B_ * H_) return;
  int b = i >> 9, hh = i & (H_ - 1);
  float m = fg[i];
  float s = 1.f;
  float t = cg_old[i];
  const float* fip = fi + (size_t)b * L_ * H_ + hh;
  const float* cp = c_new + (size_t)b * L_ * H_ + hh;
  const float* mp = maskf + b * L_;
  for (int l = 0; l < L_; ++l) {
    if (mp[l] > 0.f) {
      float xv = fip[(size_t)l * H_];
      float vv = cp[(size_t)l * H_];
      if (xv > m) {
        float sc = expf(m - xv);
        s = s * sc + 1.f;
        t = t * sc + vv;
        m = xv;
      } else {
        float e = expf(xv - m);
        s += e;
        t += e * vv;
      }
    }
  }
  float cgn = t / s;
  cg_new[i] = cgn;
  g_new[i] = og[i] * tanhf(cgn);
}

// ---------------- final head ----------------
__global__ void final1_kernel(const float* __restrict__ g,
                              const float* __restrict__ W1,
                              const float* __restrict__ b1,
                              float* __restrict__ t1) {
  int i = blockIdx.x * blockDim.x + threadIdx.x;  // B * 2H
  if (i >= B_ * 2 * H_) return;
  int b = i >> 10, j = i & (2 * H_ - 1);
  float acc = b1[j];
  const float* grow = g + b * H_;
  for (int k = 0; k < H_; ++k)
    acc = fmaf(grow[k], W1[(size_t)k * (2 * H_) + j], acc);
  t1[i] = tanhf(acc);
}

__global__ void final2_kernel(const float* __restrict__ t1,
                              const float* __restrict__ W2,
                              const float* __restrict__ b2,
                              float* __restrict__ out) {
  int b = threadIdx.x;
  if (b >= B_) return;
  float lg[DOUT_];
  const float* trow = t1 + b * 2 * H_;
#pragma unroll
  for (int d = 0; d < DOUT_; ++d) lg[d] = b2[d];
  for (int k = 0; k < 2 * H_; ++k) {
    float tv = trow[k];
#pragma unroll
    for (int d = 0; d < DOUT_; ++d)
      lg[d] = fmaf(tv, W2[(size_t)k * DOUT_ + d], lg[d]);
  }
  float m = lg[0];
#pragma unroll
  for (int d = 1; d < DOUT_; ++d) m = fmaxf(m, lg[d]);
  float s = 0.f;
#pragma unroll
  for (int d = 0; d < DOUT_; ++d) s += expf(lg[d] - m);
  float ls = logf(s);
#pragma unroll
  for (int d = 0; d < DOUT_; ++d) out[b * DOUT_ + d] = lg[d] - m - ls;
}

// ---------------- host ----------------
extern "C" void kernel_launch(void* const* d_in, const int* in_sizes, int n_in,
                              void* d_out, int out_size, void* d_ws,
                              size_t ws_size, hipStream_t stream) {
  (void)in_sizes; (void)n_in; (void)out_size; (void)ws_size;
  const int* tokens = (const int*)d_in[0];
  const int* lengths = (const int*)d_in[1];
  const float* embed = (const float*)d_in[2];
  const float* W0 = (const float*)d_in[3];
  const float* b0 = (const float*)d_in[4];
  const float* Wg = (const float*)d_in[5];
  const float* bg = (const float*)d_in[6];
  const float* Wgf = (const float*)d_in[7];
  const float* bgf = (const float*)d_in[8];
  const float* Wfi = (const float*)d_in[9];
  const float* bfi = (const float*)d_in[10];
  const float* Wgo = (const float*)d_in[11];
  const float* bgo = (const float*)d_in[12];
  const float* W1 = (const float*)d_in[13];
  const float* b1 = (const float*)d_in[14];
  const float* W2 = (const float*)d_in[15];
  const float* b2 = (const float*)d_in[16];
  float* out = (float*)d_out;

  float* ws = (float*)d_ws;
  size_t off = 0;
  auto alloc = [&](size_t n) { float* p = ws + off; off += n; return p; };
  float* x = alloc((size_t)B_ * L_ * E_);
  float* maskf = alloc(B_ * L_);
  float* invlens = alloc(B_);
  float* hb0 = alloc((size_t)B_ * L_ * H_);
  float* hb1 = alloc((size_t)B_ * L_ * H_);
  float* cb0 = alloc((size_t)B_ * L_ * H_);
  float* cb1 = alloc((size_t)B_ * L_ * H_);
  float* gb0 = alloc(B_ * H_);
  float* gb1 = alloc(B_ * H_);
  float* cgb0 = alloc(B_ * H_);
  float* cgb1 = alloc(B_ * H_);
  float* havg = alloc(B_ * H_);
  float* fg = alloc(B_ * H_);
  float* og = alloc(B_ * H_);
  float* gates = alloc((size_t)B_ * L_ * G7);
  float* ctx = alloc((size_t)B_ * L_ * CTXK);
  // aliases into the ctx region (dead by the time these are used):
  float* ficat = ctx;                              // [B*L, 2H]
  float* fi = ctx + (size_t)B_ * L_ * (2 * H_);    // [B*L, H]
  float* t1 = ctx;                                 // [B, 2H] final stage

  dim3 thr(16, 16);

  mask_lens_kernel<<<(B_ * L_ + 255) / 256, 256, 0, stream>>>(lengths, maskf,
                                                              invlens);
  embed_kernel<<<(B_ * L_ * E_ + 255) / 256, 256, 0, stream>>>(tokens, embed, x);
  // h0 = tanh(x @ W0 + b0) * mask
  gemm_bias<<<dim3(H_ / 64, (B_ * L_) / 64), thr, 0, stream>>>(
      x, W0, b0, maskf, hb0, B_ * L_, H_, E_, 1);
  reduce_mean_kernel<<<(B_ * H_ + 255) / 256, 256, 0, stream>>>(hb0, invlens,
                                                                gb0);
  fill_zero<<<(B_ * L_ * H_ + 255) / 256, 256, 0, stream>>>(cb0, B_ * L_ * H_);
  fill_zero<<<(B_ * H_ + 255) / 256, 256, 0, stream>>>(cgb0, B_ * H_);

  float* hb[2] = {hb0, hb1};
  float* cb[2] = {cb0, cb1};
  float* gbb[2] = {gb0, gb1};
  float* cgb[2] = {cgb0, cgb1};
  int cur = 0;
  for (int step = 0; step < NSTEP; ++step) {
    int nxt = cur ^ 1;
    build_ctx_kernel<<<dim3((CTXK + 255) / 256, B_ * L_), 256, 0, stream>>>(
        hb[cur], x, gbb[cur], ctx);
    gemm_bias<<<dim3(G7 / 64, (B_ * L_) / 64), thr, 0, stream>>>(
        ctx, Wg, bg, nullptr, gates, B_ * L_, G7, CTXK, 0);
    cell_update_kernel<<<(B_ * L_ * H_ + 255) / 256, 256, 0, stream>>>(
        gates, cb[cur], cgb[cur], maskf, hb[nxt], cb[nxt]);
    reduce_mean_kernel<<<(B_ * H_ + 255) / 256, 256, 0, stream>>>(
        hb[nxt], invlens, havg);
    gnode_kernel<<<(B_ * H_ + 255) / 256, 256, 0, stream>>>(
        gbb[cur], havg, Wgf, bgf, Wgo, bgo, fg, og);
    build_ficat_kernel<<<dim3((2 * H_ + 255) / 256, B_ * L_), 256, 0, stream>>>(
        gbb[cur], hb[nxt], ficat);
    gemm_bias<<<dim3(H_ / 64, (B_ * L_) / 64), thr, 0, stream>>>(
        ficat, Wfi, bfi, nullptr, fi, B_ * L_, H_, 2 * H_, 0);
    slot_update_kernel<<<(B_ * H_ + 255) / 256, 256, 0, stream>>>(
        fg, fi, og, cb[nxt], cgb[cur], maskf, cgb[nxt], gbb[nxt]);
    cur = nxt;
  }
  final1_kernel<<<(B_ * 2 * H_ + 255) / 256, 256, 0, stream>>>(gbb[cur], W1, b1,
                                                               t1);
  final2_kernel<<<1, 64, 0, stream>>>(t1, W2, b2, out);
}

// Round 2
// 1791.397 us; speedup vs baseline: 3.7296x; 3.7296x over previous
//
#include <hip/hip_runtime.h>
#include <hip/hip_bf16.h>
#include <math.h>

#define B_ 32
#define L_ 128
#define E_ 300
#define H_ 512
#define DOUT_ 5
#define NSTEP 5
#define CTXK 2348   // 3H + E + H
#define CTXKP 2368  // padded to 74*32
#define G7 3584     // 7H
#define FIK 1024    // 2H (already %32==0)

using bf16x8 = __attribute__((ext_vector_type(8))) __bf16;
using f32x4 = __attribute__((ext_vector_type(4))) float;

__device__ __forceinline__ void gload16(const void* g, void* l) {
  __builtin_amdgcn_global_load_lds(
      (const __attribute__((address_space(1))) void*)g,
      (__attribute__((address_space(3))) void*)l, 16, 0, 0);
}

// ---------------- helpers ----------------
__global__ void fill_zero(float* __restrict__ p, int n) {
  int i = blockIdx.x * blockDim.x + threadIdx.x;
  if (i < n) p[i] = 0.f;
}

__global__ void mask_lens_kernel(const int* __restrict__ lengths,
                                 float* __restrict__ maskf,
                                 float* __restrict__ invlens) {
  int i = blockIdx.x * blockDim.x + threadIdx.x;  // over B*L
  if (i < B_ * L_) {
    int b = i >> 7, l = i & 127;
    maskf[i] = (l < lengths[b]) ? 1.f : 0.f;
    if (l == 0) {
      float le = (float)lengths[b];
      invlens[b] = 1.f / fmaxf(le, 1.f);
    }
  }
}

__global__ void embed_kernel(const int* __restrict__ tokens,
                             const float* __restrict__ embed,
                             float* __restrict__ x) {
  int i = blockIdx.x * blockDim.x + threadIdx.x;  // over B*L*E
  if (i < B_ * L_ * E_) {
    int e = i % E_;
    int bl = i / E_;
    x[i] = embed[(size_t)tokens[bl] * E_ + e];
  }
}

// transpose + fp32->bf16 cast: Wt[n][k] = W[k][n], zero-padded to KPad rows of k.
// grid: (KPad/64, Ncols/64), block 256.
__global__ __launch_bounds__(256) void transpose_to_bf16(
    const float* __restrict__ W, __hip_bfloat16* __restrict__ Wt, int Kreal,
    int Ncols, int KPad) {
  __shared__ float tile[64][65];
  const int k0 = blockIdx.x * 64, n0 = blockIdx.y * 64;
  const int t = threadIdx.x;
  const int nn = t & 63, kk0 = t >> 6;
#pragma unroll
  for (int p = 0; p < 16; ++p) {
    int kk = kk0 + p * 4;
    int gk = k0 + kk;
    tile[kk][nn] = (gk < Kreal) ? W[(size_t)gk * Ncols + n0 + nn] : 0.f;
  }
  __syncthreads();
#pragma unroll
  for (int p = 0; p < 2; ++p) {
    int r = (t >> 3) + p * 32;
    int kb = (t & 7) * 8;
    union { ushort h[8]; uint4 v; } u;
#pragma unroll
    for (int e = 0; e < 8; ++e) {
      __hip_bfloat16 b = __float2bfloat16(tile[kb + e][r]);
      u.h[e] = *(ushort*)&b;
    }
    *(uint4*)&Wt[(size_t)(n0 + r) * KPad + k0 + kb] = u.v;
  }
}

// ---------------- generic fp32 tiled GEMM (kept for the small init GEMM) ----
__global__ __launch_bounds__(256) void gemm_bias(
    const float* __restrict__ A, const float* __restrict__ Bm,
    const float* __restrict__ bias, const float* __restrict__ rowscale,
    float* __restrict__ C, int M, int N, int K, int act) {
  __shared__ __align__(16) float As[16][68];
  __shared__ __align__(16) float Bs[16][64];
  const int tx = threadIdx.x, ty = threadIdx.y;
  const int tid = ty * 16 + tx;
  const int rowBase = blockIdx.y * 64;
  const int colBase = blockIdx.x * 64;
  float acc[4][4] = {{0.f}};
  const int numT = (K + 15) >> 4;
  for (int t = 0; t < numT; ++t) {
    const int k0 = t << 4;
#pragma unroll
    for (int i = 0; i < 4; ++i) {
      int lin = tid + i * 256;
      int r = lin >> 4, cc = lin & 15;
      int gk = k0 + cc;
      As[cc][r] = (gk < K) ? A[(size_t)(rowBase + r) * K + gk] : 0.f;
    }
#pragma unroll
    for (int i = 0; i < 4; ++i) {
      int lin = tid + i * 256;
      int r = lin >> 6, cc = lin & 63;
      int gk = k0 + r;
      Bs[r][cc] = (gk < K) ? Bm[(size_t)gk * N + colBase + cc] : 0.f;
    }
    __syncthreads();
#pragma unroll
    for (int kk = 0; kk < 16; ++kk) {
      float4 a4 = *(const float4*)&As[kk][ty * 4];
      float4 b4 = *(const float4*)&Bs[kk][tx * 4];
      float av[4] = {a4.x, a4.y, a4.z, a4.w};
      float bv[4] = {b4.x, b4.y, b4.z, b4.w};
#pragma unroll
      for (int i = 0; i < 4; ++i)
#pragma unroll
        for (int j = 0; j < 4; ++j)
          acc[i][j] = fmaf(av[i], bv[j], acc[i][j]);
    }
    __syncthreads();
  }
#pragma unroll
  for (int i = 0; i < 4; ++i) {
    int row = rowBase + ty * 4 + i;
    float rs = rowscale ? rowscale[row] : 1.f;
#pragma unroll
    for (int j = 0; j < 4; ++j) {
      int col = colBase + tx * 4 + j;
      float v = acc[i][j] + bias[col];
      if (act == 1) v = tanhf(v);
      v *= rs;
      C[(size_t)row * N + col] = v;
    }
  }
}

// ---------------- bf16 MFMA GEMM: C[M,N] = A[M,KP] @ Bt[N,KP]^T + bias -------
// m97 structure: 128x128 tile, 4 waves, 16x16x32 MFMA, global_load_lds w=16.
// Requires M%128==0, N%128==0, KP%32==0; A/Bt rows 16B-aligned.
__global__ __launch_bounds__(256) void gemm_bf16_mfma(
    const __hip_bfloat16* __restrict__ A, const __hip_bfloat16* __restrict__ Bt,
    const float* __restrict__ bias, float* __restrict__ C, int M, int N,
    int KP) {
  __shared__ ushort As[128 * 32];
  __shared__ ushort Bs[128 * 32];
  const int tid = threadIdx.x;
  const int lane = tid & 63;
  const int w = tid >> 6;
  const int wr = w >> 1, wc = w & 1;
  const int rowBase = blockIdx.y * 128, colBase = blockIdx.x * 128;
  const int l15 = lane & 15, l4 = lane >> 4;
  f32x4 acc[4][4] = {};

  const int c0 = tid, c1 = tid + 256;
  const size_t aOff0 = (size_t)(rowBase + (c0 >> 2)) * KP + (c0 & 3) * 8;
  const size_t aOff1 = (size_t)(rowBase + (c1 >> 2)) * KP + (c1 & 3) * 8;
  const size_t bOff0 = (size_t)(colBase + (c0 >> 2)) * KP + (c0 & 3) * 8;
  const size_t bOff1 = (size_t)(colBase + (c1 >> 2)) * KP + (c1 & 3) * 8;

  const int nIter = KP >> 5;
  for (int t = 0; t < nIter; ++t) {
    const int k0 = t << 5;
    gload16(&A[aOff0 + k0], &As[c0 * 8]);
    gload16(&Bt[bOff0 + k0], &Bs[c0 * 8]);
    gload16(&A[aOff1 + k0], &As[c1 * 8]);
    gload16(&Bt[bOff1 + k0], &Bs[c1 * 8]);
    __syncthreads();
    bf16x8 aF[4], bF[4];
#pragma unroll
    for (int m = 0; m < 4; ++m)
      aF[m] = *(const bf16x8*)&As[(wr * 64 + m * 16 + l15) * 32 + l4 * 8];
#pragma unroll
    for (int n = 0; n < 4; ++n)
      bF[n] = *(const bf16x8*)&Bs[(wc * 64 + n * 16 + l15) * 32 + l4 * 8];
#pragma unroll
    for (int m = 0; m < 4; ++m)
#pragma unroll
      for (int n = 0; n < 4; ++n)
        acc[m][n] = __builtin_amdgcn_mfma_f32_16x16x32_bf16(aF[m], bF[n],
                                                            acc[m][n], 0, 0, 0);
    __syncthreads();
  }
#pragma unroll
  for (int m = 0; m < 4; ++m) {
#pragma unroll
    for (int n = 0; n < 4; ++n) {
      int col = colBase + wc * 64 + n * 16 + l15;
      float bv = bias[col];
#pragma unroll
      for (int j = 0; j < 4; ++j) {
        int row = rowBase + wr * 64 + m * 16 + l4 * 4 + j;
        C[(size_t)row * N + col] = acc[m][n][j] + bv;
      }
    }
  }
}

// ---------------- per-step kernels ----------------
__global__ void build_ctx_bf16_kernel(const float* __restrict__ h,
                                      const float* __restrict__ x,
                                      const float* __restrict__ g,
                                      __hip_bfloat16* __restrict__ ctxb) {
  int k = blockIdx.x * blockDim.x + threadIdx.x;
  int bl = blockIdx.y;
  if (k >= CTXKP) return;
  int b = bl >> 7, l = bl & 127;
  float v;
  if (k < H_) {
    v = (l >= 1) ? h[(size_t)(bl - 1) * H_ + k] : 0.f;
  } else if (k < 2 * H_) {
    v = h[(size_t)bl * H_ + (k - H_)];
  } else if (k < 3 * H_) {
    v = (l < L_ - 1) ? h[(size_t)(bl + 1) * H_ + (k - 2 * H_)] : 0.f;
  } else if (k < 3 * H_ + E_) {
    v = x[(size_t)bl * E_ + (k - 3 * H_)];
  } else if (k < CTXK) {
    v = g[(size_t)b * H_ + (k - 3 * H_ - E_)];
  } else {
    v = 0.f;  // K padding
  }
  ctxb[(size_t)bl * CTXKP + k] = __float2bfloat16(v);
}

__global__ void cell_update_kernel(const float* __restrict__ gates,
                                   const float* __restrict__ c_old,
                                   const float* __restrict__ cg_old,
                                   const float* __restrict__ maskf,
                                   float* __restrict__ h_new,
                                   float* __restrict__ c_new) {
  int idx = blockIdx.x * blockDim.x + threadIdx.x;  // B*L*H
  if (idx >= B_ * L_ * H_) return;
  int hh = idx & (H_ - 1);
  int bl = idx >> 9;
  int b = bl >> 7, l = bl & 127;
  const float* gr_ = gates + (size_t)bl * G7;
  float gi = gr_[hh], gl = gr_[H_ + hh], gf = gr_[2 * H_ + hh],
        grr = gr_[3 * H_ + hh], gs = gr_[4 * H_ + hh],
        go = gr_[5 * H_ + hh], gu = gr_[6 * H_ + hh];
  float m = fmaxf(fmaxf(fmaxf(gi, gl), fmaxf(gf, grr)), gs);
  float ei = expf(gi - m), el = expf(gl - m), ef = expf(gf - m),
        er = expf(grr - m), es = expf(gs - m);
  float inv = 1.f / (ei + el + ef + er + es);
  float o = 1.f / (1.f + expf(-go));
  float u = tanhf(gu);
  float cprev = (l >= 1) ? c_old[idx - H_] : 0.f;
  float ccur = c_old[idx];
  float cnext = (l < L_ - 1) ? c_old[idx + H_] : 0.f;
  float cgv = cg_old[b * H_ + hh];
  float mk = maskf[bl];
  float cn = (el * cprev + ef * ccur + er * cnext + es * cgv + ei * u) * inv * mk;
  float hn = o * tanhf(cn) * mk;
  c_new[idx] = cn;
  h_new[idx] = hn;
}

__global__ void reduce_mean_kernel(const float* __restrict__ hin,
                                   const float* __restrict__ invlens,
                                   float* __restrict__ out) {
  int i = blockIdx.x * blockDim.x + threadIdx.x;  // B*H
  if (i >= B_ * H_) return;
  int b = i >> 9;
  const float* p = hin + (size_t)b * L_ * H_ + (i & (H_ - 1));
  float s = 0.f;
#pragma unroll 4
  for (int l = 0; l < L_; ++l) s += p[(size_t)l * H_];
  out[i] = s * invlens[b];
}

__global__ void gnode_kernel(const float* __restrict__ g,
                             const float* __restrict__ havg,
                             const float* __restrict__ Wgf,
                             const float* __restrict__ bgf,
                             const float* __restrict__ Wgo,
                             const float* __restrict__ bgo,
                             float* __restrict__ fg, float* __restrict__ og) {
  int i = blockIdx.x * blockDim.x + threadIdx.x;  // B*H
  if (i >= B_ * H_) return;
  int b = i >> 9, hh = i & (H_ - 1);
  float af = bgf[hh], ao = bgo[hh];
  const float* grow = g + b * H_;
  const float* hrow = havg + b * H_;
  for (int k = 0; k < H_; ++k) {
    float gv = grow[k];
    af = fmaf(gv, Wgf[(size_t)k * H_ + hh], af);
    ao = fmaf(gv, Wgo[(size_t)k * H_ + hh], ao);
  }
  for (int k = 0; k < H_; ++k) {
    float hv = hrow[k];
    af = fmaf(hv, Wgf[(size_t)(H_ + k) * H_ + hh], af);
    ao = fmaf(hv, Wgo[(size_t)(H_ + k) * H_ + hh], ao);
  }
  fg[i] = af;
  og[i] = 1.f / (1.f + expf(-ao));
}

__global__ void build_ficat_bf16_kernel(const float* __restrict__ g,
                                        const float* __restrict__ h_new,
                                        __hip_bfloat16* __restrict__ ficatb) {
  int k = blockIdx.x * blockDim.x + threadIdx.x;  // 0..1023
  int bl = blockIdx.y;
  if (k >= 2 * H_) return;
  int b = bl >> 7;
  float v = (k < H_) ? g[b * H_ + k] : h_new[(size_t)bl * H_ + (k - H_)];
  ficatb[(size_t)bl * (2 * H_) + k] = __float2bfloat16(v);
}

// online softmax over L+1 slots per (b,h)
__global__ void slot_update_kernel(const float* __restrict__ fg,
                                   const float* __restrict__ fi,
                                   const float* __restrict__ og,
                                   const float* __restrict__ c_new,
                                   const float* __restrict__ cg_old,
                                   const float* __restrict__ maskf,
                                   float* __restrict__ cg_new,
                                   float* __restrict__ g_new) {
  int i = blockIdx.x * blockDim.x + threadIdx.x;  // B*H
  if (i >= B_ * H_) return;
  int b = i >> 9, hh = i & (H_ - 1);
  float m = fg[i];
  float s = 1.f;
  float t = cg_old[i];
  const float* fip = fi + (size_t)b * L_ * H_ + hh;
  const float* cp = c_new + (size_t)b * L_ * H_ + hh;
  const float* mp = maskf + b * L_;
  for (int l = 0; l < L_; ++l) {
    if (mp[l] > 0.f) {
      float xv = fip[(size_t)l * H_];
      float vv = cp[(size_t)l * H_];
      if (xv > m) {
        float sc = expf(m - xv);
        s = s * sc + 1.f;
        t = t * sc + vv;
        m = xv;
      } else {
        float e = expf(xv - m);
        s += e;
        t += e * vv;
      }
    }
  }
  float cgn = t / s;
  cg_new[i] = cgn;
  g_new[i] = og[i] * tanhf(cgn);
}

// ---------------- final head ----------------
__global__ void final1_kernel(const float* __restrict__ g,
                              const float* __restrict__ W1,
                              const float* __restrict__ b1,
                              float* __restrict__ t1) {
  int i = blockIdx.x * blockDim.x + threadIdx.x;  // B * 2H
  if (i >= B_ * 2 * H_) return;
  int b = i >> 10, j = i & (2 * H_ - 1);
  float acc = b1[j];
  const float* grow = g + b * H_;
  for (int k = 0; k < H_; ++k)
    acc = fmaf(grow[k], W1[(size_t)k * (2 * H_) + j], acc);
  t1[i] = tanhf(acc);
}

__global__ void final2_kernel(const float* __restrict__ t1,
                              const float* __restrict__ W2,
                              const float* __restrict__ b2,
                              float* __restrict__ out) {
  int b = threadIdx.x;
  if (b >= B_) return;
  float lg[DOUT_];
  const float* trow = t1 + b * 2 * H_;
#pragma unroll
  for (int d = 0; d < DOUT_; ++d) lg[d] = b2[d];
  for (int k = 0; k < 2 * H_; ++k) {
    float tv = trow[k];
#pragma unroll
    for (int d = 0; d < DOUT_; ++d)
      lg[d] = fmaf(tv, W2[(size_t)k * DOUT_ + d], lg[d]);
  }
  float m = lg[0];
#pragma unroll
  for (int d = 1; d < DOUT_; ++d) m = fmaxf(m, lg[d]);
  float s = 0.f;
#pragma unroll
  for (int d = 0; d < DOUT_; ++d) s += expf(lg[d] - m);
  float ls = logf(s);
#pragma unroll
  for (int d = 0; d < DOUT_; ++d) out[b * DOUT_ + d] = lg[d] - m - ls;
}

// ---------------- host ----------------
extern "C" void kernel_launch(void* const* d_in, const int* in_sizes, int n_in,
                              void* d_out, int out_size, void* d_ws,
                              size_t ws_size, hipStream_t stream) {
  (void)in_sizes; (void)n_in; (void)out_size; (void)ws_size;
  const int* tokens = (const int*)d_in[0];
  const int* lengths = (const int*)d_in[1];
  const float* embed = (const float*)d_in[2];
  const float* W0 = (const float*)d_in[3];
  const float* b0 = (const float*)d_in[4];
  const float* Wg = (const float*)d_in[5];
  const float* bg = (const float*)d_in[6];
  const float* Wgf = (const float*)d_in[7];
  const float* bgf = (const float*)d_in[8];
  const float* Wfi = (const float*)d_in[9];
  const float* bfi = (const float*)d_in[10];
  const float* Wgo = (const float*)d_in[11];
  const float* bgo = (const float*)d_in[12];
  const float* W1 = (const float*)d_in[13];
  const float* b1 = (const float*)d_in[14];
  const float* W2 = (const float*)d_in[15];
  const float* b2 = (const float*)d_in[16];
  float* out = (float*)d_out;

  float* ws = (float*)d_ws;
  size_t off = 0;
  auto alloc = [&](size_t n) {
    float* p = ws + off;
    off += (n + 7) & ~(size_t)7;  // 32B-align each region
    return p;
  };
  float* x = alloc((size_t)B_ * L_ * E_);
  float* maskf = alloc(B_ * L_);
  float* invlens = alloc(B_);
  float* hb0 = alloc((size_t)B_ * L_ * H_);
  float* hb1 = alloc((size_t)B_ * L_ * H_);
  float* cb0 = alloc((size_t)B_ * L_ * H_);
  float* cb1 = alloc((size_t)B_ * L_ * H_);
  float* gb0 = alloc(B_ * H_);
  float* gb1 = alloc(B_ * H_);
  float* cgb0 = alloc(B_ * H_);
  float* cgb1 = alloc(B_ * H_);
  float* havg = alloc(B_ * H_);
  float* fg = alloc(B_ * H_);
  float* og = alloc(B_ * H_);
  float* gates = alloc((size_t)B_ * L_ * G7);      // fp32 [4096][3584]
  // bf16 regions (element counts halved into float units)
  __hip_bfloat16* Wgt = (__hip_bfloat16*)alloc((size_t)G7 * CTXKP / 2);
  __hip_bfloat16* Wfit = (__hip_bfloat16*)alloc((size_t)H_ * FIK / 2);
  __hip_bfloat16* ctxb = (__hip_bfloat16*)alloc((size_t)B_ * L_ * CTXKP / 2);
  // aliases:
  __hip_bfloat16* ficatb = ctxb;                    // [4096][1024] bf16, ctx dead
  float* fi = gates;                                // [4096][512] fp32, gates dead
  float* t1 = gates + (size_t)B_ * L_ * H_;         // [32][1024] final stage

  dim3 thr(16, 16);

  mask_lens_kernel<<<(B_ * L_ + 255) / 256, 256, 0, stream>>>(lengths, maskf,
                                                              invlens);
  embed_kernel<<<(B_ * L_ * E_ + 255) / 256, 256, 0, stream>>>(tokens, embed, x);
  // one-time weight prep: Wg -> Wgt bf16 [3584][2368], Wfi -> Wfit bf16 [512][1024]
  transpose_to_bf16<<<dim3(CTXKP / 64, G7 / 64), 256, 0, stream>>>(
      Wg, Wgt, CTXK, G7, CTXKP);
  transpose_to_bf16<<<dim3(FIK / 64, H_ / 64), 256, 0, stream>>>(
      Wfi, Wfit, FIK, H_, FIK);
  // h0 = tanh(x @ W0 + b0) * mask   (small fp32 GEMM)
  gemm_bias<<<dim3(H_ / 64, (B_ * L_) / 64), thr, 0, stream>>>(
      x, W0, b0, maskf, hb0, B_ * L_, H_, E_, 1);
  reduce_mean_kernel<<<(B_ * H_ + 255) / 256, 256, 0, stream>>>(hb0, invlens,
                                                                gb0);
  fill_zero<<<(B_ * L_ * H_ + 255) / 256, 256, 0, stream>>>(cb0, B_ * L_ * H_);
  fill_zero<<<(B_ * H_ + 255) / 256, 256, 0, stream>>>(cgb0, B_ * H_);

  float* hb[2] = {hb0, hb1};
  float* cb[2] = {cb0, cb1};
  float* gbb[2] = {gb0, gb1};
  float* cgb[2] = {cgb0, cgb1};
  int cur = 0;
  for (int step = 0; step < NSTEP; ++step) {
    int nxt = cur ^ 1;
    build_ctx_bf16_kernel<<<dim3((CTXKP + 255) / 256, B_ * L_), 256, 0,
                            stream>>>(hb[cur], x, gbb[cur], ctxb);
    gemm_bf16_mfma<<<dim3(G7 / 128, (B_ * L_) / 128), 256, 0, stream>>>(
        ctxb, Wgt, bg, gates, B_ * L_, G7, CTXKP);
    cell_update_kernel<<<(B_ * L_ * H_ + 255) / 256, 256, 0, stream>>>(
        gates, cb[cur], cgb[cur], maskf, hb[nxt], cb[nxt]);
    reduce_mean_kernel<<<(B_ * H_ + 255) / 256, 256, 0, stream>>>(
        hb[nxt], invlens, havg);
    gnode_kernel<<<(B_ * H_ + 255) / 256, 256, 0, stream>>>(
        gbb[cur], havg, Wgf, bgf, Wgo, bgo, fg, og);
    build_ficat_bf16_kernel<<<dim3((2 * H_ + 255) / 256, B_ * L_), 256, 0,
                              stream>>>(gbb[cur], hb[nxt], ficatb);
    gemm_bf16_mfma<<<dim3(H_ / 128, (B_ * L_) / 128), 256, 0, stream>>>(
        ficatb, Wfit, bfi, fi, B_ * L_, H_, FIK);
    slot_update_kernel<<<(B_ * H_ + 255) / 256, 256, 0, stream>>>(
        fg, fi, og, cb[nxt], cgb[cur], maskf, cgb[nxt], gbb[nxt]);
    cur = nxt;
  }
  final1_kernel<<<(B_ * 2 * H_ + 255) / 256, 256, 0, stream>>>(gbb[cur], W1, b1,
                                                               t1);
  final2_kernel<<<1, 64, 0, stream>>>(t1, W2, b2, out);
}

// Round 3
// 1379.357 us; speedup vs baseline: 4.8437x; 1.2987x over previous
//
#include <hip/hip_runtime.h>
#include <hip/hip_bf16.h>
#include <math.h>

#define B_ 32
#define L_ 128
#define LP 130      // padded L (zero row before/after)
#define E_ 300
#define EP 320      // padded E (%32)
#define H_ 512
#define DOUT_ 5
#define NSTEP 5
#define G7 3584     // 7H
#define KG 2048     // 3H + H (hl,h,hr,g)
#define KFI 1024    // 2H (g,h)

typedef __hip_bfloat16 bf16;
using bf16x8 = __attribute__((ext_vector_type(8))) __bf16;
using f32x4 = __attribute__((ext_vector_type(4))) float;

__device__ __forceinline__ void gload16(const void* g, void* l) {
  __builtin_amdgcn_global_load_lds(
      (const __attribute__((address_space(1))) void*)g,
      (__attribute__((address_space(3))) void*)l, 16, 0, 0);
}

// ---------------- small helpers ----------------
__global__ void fill_zero(float* __restrict__ p, int n) {
  int i = blockIdx.x * blockDim.x + threadIdx.x;
  if (i < n) p[i] = 0.f;
}

__global__ void mask_lens_kernel(const int* __restrict__ lengths,
                                 float* __restrict__ maskf,
                                 float* __restrict__ invlens) {
  int i = blockIdx.x * blockDim.x + threadIdx.x;
  if (i < B_ * L_) {
    int b = i >> 7, l = i & 127;
    maskf[i] = (l < lengths[b]) ? 1.f : 0.f;
    if (l == 0) invlens[b] = 1.f / fmaxf((float)lengths[b], 1.f);
  }
}

__global__ void embed_bf16_kernel(const int* __restrict__ tokens,
                                  const float* __restrict__ embed,
                                  bf16* __restrict__ xb) {
  int i = blockIdx.x * blockDim.x + threadIdx.x;  // B*L*EP
  if (i >= B_ * L_ * EP) return;
  int e = i % EP, bl = i / EP;
  float v = (e < E_) ? embed[(size_t)tokens[bl] * E_ + e] : 0.f;
  xb[i] = __float2bfloat16(v);
}

// transpose + cast: Wt[n][k] = W[k][n]; W pre-offset; Wt pre-offset (col 0 of
// this region). grid (Kregion/64, Ncols/64), Kregion%64==0.
__global__ __launch_bounds__(256) void transpose_to_bf16(
    const float* __restrict__ W, bf16* __restrict__ Wt, int Kreal, int Ncols,
    int dstStride) {
  __shared__ float tile[64][65];
  const int k0 = blockIdx.x * 64, n0 = blockIdx.y * 64;
  const int t = threadIdx.x;
  const int nn = t & 63, kk0 = t >> 6;
#pragma unroll
  for (int p = 0; p < 16; ++p) {
    int kk = kk0 + p * 4;
    int gk = k0 + kk;
    tile[kk][nn] = (gk < Kreal) ? W[(size_t)gk * Ncols + n0 + nn] : 0.f;
  }
  __syncthreads();
#pragma unroll
  for (int p = 0; p < 2; ++p) {
    int r = (t >> 3) + p * 32;
    int kb = (t & 7) * 8;
    union { ushort h[8]; uint4 v; } u;
#pragma unroll
    for (int e = 0; e < 8; ++e) {
      bf16 b = __float2bfloat16(tile[kb + e][r]);
      u.h[e] = *(ushort*)&b;
    }
    *(uint4*)&Wt[(size_t)(n0 + r) * dstStride + k0 + kb] = u.v;
  }
}

// ---------------- bf16 MFMA GEMM (m97 structure + LDS chunk swizzle + XCD
// swizzle). C[M,N] = A[M,KP] @ Bt[N,KP]^T (+bias[col]) (+bf16 bias2d[row,col])
// (+tanh) (*rowscale[row]). OUTBF16 selects output dtype.
template <bool OUTBF16>
__global__ __launch_bounds__(256) void gemm_mfma(
    const bf16* __restrict__ A, const bf16* __restrict__ Bt,
    const float* __restrict__ bias, const bf16* __restrict__ bias2d,
    const float* __restrict__ rowscale, void* __restrict__ Cout, int N, int KP,
    int act) {
  __shared__ ushort As[128 * 32];
  __shared__ ushort Bs[128 * 32];
  const int tid = threadIdx.x;
  const int lane = tid & 63;
  const int w = tid >> 6;
  const int wr = w >> 1, wc = w & 1;
  // XCD-aware bijective block swizzle (grids here are all %8==0)
  const int nbx = gridDim.x;
  const int nwg = nbx * gridDim.y;
  int id = blockIdx.y * nbx + blockIdx.x;
  if ((nwg & 7) == 0) { int q = nwg >> 3; id = (id & 7) * q + (id >> 3); }
  const int bxi = id % nbx, byi = id / nbx;
  const int rowBase = byi * 128, colBase = bxi * 128;
  const int l15 = lane & 15, l4 = lane >> 4;
  const int pch = l4 ^ ((l15 >> 1) & 3);  // swizzled physical chunk for reads
  f32x4 acc[4][4] = {};

  // staging: linear LDS dest, inverse-swizzled global source chunk
  const int c0 = tid, c1 = tid + 256;
  const int r0 = c0 >> 2, q0 = (c0 & 3) ^ ((r0 >> 1) & 3);
  const int r1 = c1 >> 2, q1 = (c1 & 3) ^ ((r1 >> 1) & 3);
  const size_t aOff0 = (size_t)(rowBase + r0) * KP + q0 * 8;
  const size_t aOff1 = (size_t)(rowBase + r1) * KP + q1 * 8;
  const size_t bOff0 = (size_t)(colBase + r0) * KP + q0 * 8;
  const size_t bOff1 = (size_t)(colBase + r1) * KP + q1 * 8;

  const int nIter = KP >> 5;
  for (int t = 0; t < nIter; ++t) {
    const int k0 = t << 5;
    gload16(&A[aOff0 + k0], &As[c0 * 8]);
    gload16(&Bt[bOff0 + k0], &Bs[c0 * 8]);
    gload16(&A[aOff1 + k0], &As[c1 * 8]);
    gload16(&Bt[bOff1 + k0], &Bs[c1 * 8]);
    __syncthreads();
    bf16x8 aF[4], bF[4];
#pragma unroll
    for (int m = 0; m < 4; ++m)
      aF[m] = *(const bf16x8*)&As[(wr * 64 + m * 16 + l15) * 32 + pch * 8];
#pragma unroll
    for (int n = 0; n < 4; ++n)
      bF[n] = *(const bf16x8*)&Bs[(wc * 64 + n * 16 + l15) * 32 + pch * 8];
#pragma unroll
    for (int m = 0; m < 4; ++m)
#pragma unroll
      for (int n = 0; n < 4; ++n)
        acc[m][n] = __builtin_amdgcn_mfma_f32_16x16x32_bf16(aF[m], bF[n],
                                                            acc[m][n], 0, 0, 0);
    __syncthreads();
  }
#pragma unroll
  for (int m = 0; m < 4; ++m) {
#pragma unroll
    for (int n = 0; n < 4; ++n) {
      int col = colBase + wc * 64 + n * 16 + l15;
      float bv = bias ? bias[col] : 0.f;
#pragma unroll
      for (int j = 0; j < 4; ++j) {
        int row = rowBase + wr * 64 + m * 16 + l4 * 4 + j;
        float v = acc[m][n][j] + bv;
        if (bias2d) v += __bfloat162float(bias2d[(size_t)row * N + col]);
        if (act == 1) v = tanhf(v);
        if (rowscale) v *= rowscale[row];
        if (OUTBF16)
          ((bf16*)Cout)[(size_t)row * N + col] = __float2bfloat16(v);
        else
          ((float*)Cout)[(size_t)row * N + col] = v;
      }
    }
  }
}

// ---------------- A-matrix builders (bf16 gather, 16B per thread) ----------
__global__ void build_gates_A(const bf16* __restrict__ hpad,
                              const bf16* __restrict__ gcur,
                              bf16* __restrict__ Ag) {
  int i = blockIdx.x * blockDim.x + threadIdx.x;  // B*L*KG/8
  if (i >= (B_ * L_ * KG) / 8) return;
  int row = i >> 8;           // KG/8 = 256
  int k0 = (i & 255) * 8;
  int b = row >> 7, l = row & 127;
  int chunk = k0 >> 9, kk = k0 & 511;
  const bf16* src = (chunk < 3)
                        ? (hpad + ((size_t)(b * LP + l + chunk)) * H_ + kk)
                        : (gcur + (size_t)b * H_ + kk);
  *(uint4*)&Ag[(size_t)row * KG + k0] = *(const uint4*)src;
}

__global__ void build_fi_A(const bf16* __restrict__ hpad,
                           const bf16* __restrict__ gcur,
                           bf16* __restrict__ Af) {
  int i = blockIdx.x * blockDim.x + threadIdx.x;  // B*L*KFI/8
  if (i >= (B_ * L_ * KFI) / 8) return;
  int row = i >> 7;           // KFI/8 = 128
  int k0 = (i & 127) * 8;
  int b = row >> 7, l = row & 127;
  int chunk = k0 >> 9, kk = k0 & 511;
  const bf16* src = (chunk == 0)
                        ? (gcur + (size_t)b * H_ + kk)
                        : (hpad + ((size_t)(b * LP + l + 1)) * H_ + kk);
  *(uint4*)&Af[(size_t)row * KFI + k0] = *(const uint4*)src;
}

// ---------------- per-step cell math ----------------
__global__ void cell_update_v2(const bf16* __restrict__ gates,
                               const float* __restrict__ c_old,
                               const float* __restrict__ cg_old,
                               const float* __restrict__ maskf,
                               bf16* __restrict__ hpad,
                               float* __restrict__ c_new) {
  int idx = blockIdx.x * blockDim.x + threadIdx.x;  // B*L*H
  if (idx >= B_ * L_ * H_) return;
  int hh = idx & (H_ - 1);
  int bl = idx >> 9;
  int b = bl >> 7, l = bl & 127;
  const bf16* gr = gates + (size_t)bl * G7;
  float gi = __bfloat162float(gr[hh]);
  float gl = __bfloat162float(gr[H_ + hh]);
  float gf = __bfloat162float(gr[2 * H_ + hh]);
  float grr = __bfloat162float(gr[3 * H_ + hh]);
  float gs = __bfloat162float(gr[4 * H_ + hh]);
  float go = __bfloat162float(gr[5 * H_ + hh]);
  float gu = __bfloat162float(gr[6 * H_ + hh]);
  float m = fmaxf(fmaxf(fmaxf(gi, gl), fmaxf(gf, grr)), gs);
  float ei = expf(gi - m), el = expf(gl - m), ef = expf(gf - m),
        er = expf(grr - m), es = expf(gs - m);
  float inv = 1.f / (ei + el + ef + er + es);
  float o = 1.f / (1.f + expf(-go));
  float u = tanhf(gu);
  float cprev = (l >= 1) ? c_old[idx - H_] : 0.f;
  float ccur = c_old[idx];
  float cnext = (l < L_ - 1) ? c_old[idx + H_] : 0.f;
  float cgv = cg_old[b * H_ + hh];
  float mk = maskf[bl];
  float cn =
      (el * cprev + ef * ccur + er * cnext + es * cgv + ei * u) * inv * mk;
  float hn = o * tanhf(cn) * mk;
  c_new[idx] = cn;
  hpad[((size_t)(b * LP + l + 1)) * H_ + hh] = __float2bfloat16(hn);
}

// deterministic parallel mean over L from bf16 hpad -> fp32 (optionally bf16)
__global__ __launch_bounds__(256) void reduce_mean_v2(
    const bf16* __restrict__ hpad, const float* __restrict__ invlens,
    float* __restrict__ outf, bf16* __restrict__ outb) {
  __shared__ float sm[4][64];
  int b = blockIdx.y, h0 = blockIdx.x * 64;
  int lg = threadIdx.x >> 6, hh = threadIdx.x & 63;
  float s = 0.f;
  for (int l = lg * 32; l < lg * 32 + 32; ++l)
    s += __bfloat162float(hpad[((size_t)(b * LP + l + 1)) * H_ + h0 + hh]);
  sm[lg][hh] = s;
  __syncthreads();
  if (threadIdx.x < 64) {
    int t = threadIdx.x;
    float m = (sm[0][t] + sm[1][t] + sm[2][t] + sm[3][t]) * invlens[b];
    outf[b * H_ + h0 + t] = m;
    if (outb) outb[b * H_ + h0 + t] = __float2bfloat16(m);
  }
}

// fg/og tiny GEMMs, 4-way K-split + LDS reduce. grid (8, B, 2)
__global__ __launch_bounds__(256) void gnode_v2(
    const float* __restrict__ g, const float* __restrict__ havg,
    const float* __restrict__ Wgf, const float* __restrict__ bgf,
    const float* __restrict__ Wgo, const float* __restrict__ bgo,
    float* __restrict__ fg, float* __restrict__ og) {
  __shared__ float sm[4][64];
  int h0 = blockIdx.x * 64, b = blockIdx.y, which = blockIdx.z;
  const float* W = which ? Wgo : Wgf;
  const float* bias = which ? bgo : bgf;
  int o = threadIdx.x & 63, kp = threadIdx.x >> 6;
  const float* ing = g + b * H_;
  const float* inh = havg + b * H_;
  float acc = 0.f;
  int ks = kp * 256;
#pragma unroll 4
  for (int k = ks; k < ks + 256; ++k) {
    float iv = (k < H_) ? ing[k] : inh[k - H_];
    acc = fmaf(iv, W[(size_t)k * H_ + h0 + o], acc);
  }
  sm[kp][o] = acc;
  __syncthreads();
  if (threadIdx.x < 64) {
    int t = threadIdx.x;
    float v = sm[0][t] + sm[1][t] + sm[2][t] + sm[3][t] + bias[h0 + t];
    if (which)
      og[b * H_ + h0 + t] = 1.f / (1.f + expf(-v));
    else
      fg[b * H_ + h0 + t] = v;
  }
}

// online softmax over L+1 slots, 4 waves split L, LDS merge. grid B*H/64.
__global__ __launch_bounds__(256) void slot_update_v2(
    const float* __restrict__ fg, const float* __restrict__ fi,
    const float* __restrict__ og, const float* __restrict__ c_new,
    const float* __restrict__ cg_old, const float* __restrict__ maskf,
    float* __restrict__ cg_new, float* __restrict__ g_new,
    bf16* __restrict__ gcur) {
  __shared__ float sm[4][64], ss[4][64], st[4][64];
  int lane = threadIdx.x & 63, w = threadIdx.x >> 6;
  int i = blockIdx.x * 64 + lane;
  int b = i >> 9, h = i & (H_ - 1);
  const float* mp = maskf + b * L_;
  float m = -3.0e38f, s = 0.f, t = 0.f;
  for (int l = w * 32; l < w * 32 + 32; ++l) {
    if (mp[l] > 0.f) {
      float xv = fi[((size_t)b * L_ + l) * H_ + h];
      float vv = c_new[((size_t)b * L_ + l) * H_ + h];
      float m2 = fmaxf(m, xv);
      float sc = expf(m - m2);
      float e = expf(xv - m2);
      s = s * sc + e;
      t = t * sc + e * vv;
      m = m2;
    }
  }
  sm[w][lane] = m;
  ss[w][lane] = s;
  st[w][lane] = t;
  __syncthreads();
  if (threadIdx.x < 64) {
    int tt = threadIdx.x;
    int i0 = blockIdx.x * 64 + tt;
    float mm = sm[0][tt], s0 = ss[0][tt], t0 = st[0][tt];
#pragma unroll
    for (int k = 1; k < 4; ++k) {
      float mk = sm[k][tt];
      float m2 = fmaxf(mm, mk);
      float e1 = expf(mm - m2), e2 = expf(mk - m2);
      s0 = s0 * e1 + ss[k][tt] * e2;
      t0 = t0 * e1 + st[k][tt] * e2;
      mm = m2;
    }
    float f = fg[i0], cg = cg_old[i0];
    float m2 = fmaxf(mm, f);
    float e1 = expf(mm - m2), e0 = expf(f - m2);
    s0 = s0 * e1 + e0;
    t0 = t0 * e1 + cg * e0;
    float cgn = t0 / s0;
    float gn = og[i0] * tanhf(cgn);
    cg_new[i0] = cgn;
    g_new[i0] = gn;
    gcur[i0] = __float2bfloat16(gn);
  }
}

// ---------------- init conversions ----------------
__global__ void convert_h0(const float* __restrict__ h0,
                           bf16* __restrict__ hpad) {
  int i = blockIdx.x * blockDim.x + threadIdx.x;  // B*L*H
  if (i >= B_ * L_ * H_) return;
  int hh = i & (H_ - 1);
  int bl = i >> 9, b = bl >> 7, l = bl & 127;
  hpad[((size_t)(b * LP + l + 1)) * H_ + hh] = __float2bfloat16(h0[i]);
}

__global__ void fill_pad(bf16* __restrict__ hpad) {
  int i = blockIdx.x * blockDim.x + threadIdx.x;  // B*2*H
  if (i >= B_ * 2 * H_) return;
  int hh = i & (H_ - 1);
  int r = (i >> 9) & 1, b = i >> 10;
  hpad[((size_t)(b * LP + r * (LP - 1))) * H_ + hh] = __float2bfloat16(0.f);
}

// ---------------- final head ----------------
__global__ void final1_kernel(const float* __restrict__ g,
                              const float* __restrict__ W1,
                              const float* __restrict__ b1,
                              float* __restrict__ t1) {
  int i = blockIdx.x * blockDim.x + threadIdx.x;  // B * 2H
  if (i >= B_ * 2 * H_) return;
  int b = i >> 10, j = i & (2 * H_ - 1);
  float acc = b1[j];
  const float* grow = g + b * H_;
  for (int k = 0; k < H_; ++k)
    acc = fmaf(grow[k], W1[(size_t)k * (2 * H_) + j], acc);
  t1[i] = tanhf(acc);
}

__global__ void final2_kernel(const float* __restrict__ t1,
                              const float* __restrict__ W2,
                              const float* __restrict__ b2,
                              float* __restrict__ out) {
  int b = threadIdx.x;
  if (b >= B_) return;
  float lg[DOUT_];
  const float* trow = t1 + b * 2 * H_;
#pragma unroll
  for (int d = 0; d < DOUT_; ++d) lg[d] = b2[d];
  for (int k = 0; k < 2 * H_; ++k) {
    float tv = trow[k];
#pragma unroll
    for (int d = 0; d < DOUT_; ++d)
      lg[d] = fmaf(tv, W2[(size_t)k * DOUT_ + d], lg[d]);
  }
  float m = lg[0];
#pragma unroll
  for (int d = 1; d < DOUT_; ++d) m = fmaxf(m, lg[d]);
  float s = 0.f;
#pragma unroll
  for (int d = 0; d < DOUT_; ++d) s += expf(lg[d] - m);
  float ls = logf(s);
#pragma unroll
  for (int d = 0; d < DOUT_; ++d) out[b * DOUT_ + d] = lg[d] - m - ls;
}

// ---------------- host ----------------
extern "C" void kernel_launch(void* const* d_in, const int* in_sizes, int n_in,
                              void* d_out, int out_size, void* d_ws,
                              size_t ws_size, hipStream_t stream) {
  (void)in_sizes; (void)n_in; (void)out_size; (void)ws_size;
  const int* tokens = (const int*)d_in[0];
  const int* lengths = (const int*)d_in[1];
  const float* embed = (const float*)d_in[2];
  const float* W0 = (const float*)d_in[3];
  const float* b0 = (const float*)d_in[4];
  const float* Wg = (const float*)d_in[5];
  const float* bg = (const float*)d_in[6];
  const float* Wgf = (const float*)d_in[7];
  const float* bgf = (const float*)d_in[8];
  const float* Wfi = (const float*)d_in[9];
  const float* bfi = (const float*)d_in[10];
  const float* Wgo = (const float*)d_in[11];
  const float* bgo = (const float*)d_in[12];
  const float* W1 = (const float*)d_in[13];
  const float* b1 = (const float*)d_in[14];
  const float* W2 = (const float*)d_in[15];
  const float* b2 = (const float*)d_in[16];
  float* out = (float*)d_out;

  float* ws = (float*)d_ws;
  size_t off = 0;
  auto alloc = [&](size_t nf) {
    float* p = ws + off;
    off += (nf + 7) & ~(size_t)7;
    return p;
  };
  bf16* xb = (bf16*)alloc((size_t)B_ * L_ * EP / 2);        // [4096][320]
  float* maskf = alloc(B_ * L_);
  float* invlens = alloc(B_);
  bf16* hpad = (bf16*)alloc((size_t)B_ * LP * H_ / 2);      // [32][130][512]
  float* cb0 = alloc((size_t)B_ * L_ * H_);
  float* cb1 = alloc((size_t)B_ * L_ * H_);
  float* g = alloc(B_ * H_);
  bf16* gcur = (bf16*)alloc(B_ * H_ / 2);
  float* cgb0 = alloc(B_ * H_);
  float* cgb1 = alloc(B_ * H_);
  float* havg = alloc(B_ * H_);
  float* fg = alloc(B_ * H_);
  float* og = alloc(B_ * H_);
  bf16* gatesb = (bf16*)alloc((size_t)B_ * L_ * G7 / 2);    // [4096][3584]
  bf16* Ag = (bf16*)alloc((size_t)B_ * L_ * KG / 2);        // [4096][2048]
  bf16* xg = (bf16*)alloc((size_t)B_ * L_ * G7 / 2);        // [4096][3584]
  bf16* Wgt = (bf16*)alloc((size_t)G7 * KG / 2);            // [3584][2048]
  bf16* Wg3t = (bf16*)alloc((size_t)G7 * EP / 2);           // [3584][320]
  bf16* W0t = (bf16*)alloc((size_t)H_ * EP / 2);            // [512][320]
  bf16* Wfit = (bf16*)alloc((size_t)H_ * KFI / 2);          // [512][1024]
  float* fi = alloc((size_t)B_ * L_ * H_);                  // [4096][512] fp32
  // aliases (regions dead at time of use):
  bf16* Afi = Ag;           // [4096][1024] bf16
  float* h0tmp = fi;        // [4096][512] fp32 (init only)
  float* t1 = fi;           // [32][1024] fp32 (final only)

  // ---- init ----
  mask_lens_kernel<<<(B_ * L_ + 255) / 256, 256, 0, stream>>>(lengths, maskf,
                                                              invlens);
  embed_bf16_kernel<<<(B_ * L_ * EP + 255) / 256, 256, 0, stream>>>(tokens,
                                                                    embed, xb);
  // weight prep
  transpose_to_bf16<<<dim3(1536 / 64, G7 / 64), 256, 0, stream>>>(
      Wg, Wgt, 1536, G7, KG);                          // hl,h,hr rows
  transpose_to_bf16<<<dim3(512 / 64, G7 / 64), 256, 0, stream>>>(
      Wg + (size_t)1836 * G7, Wgt + 1536, 512, G7, KG);  // g rows
  transpose_to_bf16<<<dim3(EP / 64, G7 / 64), 256, 0, stream>>>(
      Wg + (size_t)1536 * G7, Wg3t, 300, G7, EP);        // x rows
  transpose_to_bf16<<<dim3(EP / 64, H_ / 64), 256, 0, stream>>>(W0, W0t, 300,
                                                                H_, EP);
  transpose_to_bf16<<<dim3(KFI / 64, H_ / 64), 256, 0, stream>>>(Wfi, Wfit,
                                                                 KFI, H_, KFI);
  // xg = xb @ Wg3t + bg  (bf16 out, step-invariant)
  gemm_mfma<true><<<dim3(G7 / 128, (B_ * L_) / 128), 256, 0, stream>>>(
      xb, Wg3t, bg, nullptr, nullptr, xg, G7, EP, 0);
  // h0 = tanh(xb @ W0t + b0) * mask
  gemm_mfma<false><<<dim3(H_ / 128, (B_ * L_) / 128), 256, 0, stream>>>(
      xb, W0t, b0, nullptr, maskf, h0tmp, H_, EP, 1);
  fill_pad<<<(B_ * 2 * H_ + 255) / 256, 256, 0, stream>>>(hpad);
  convert_h0<<<(B_ * L_ * H_ + 255) / 256, 256, 0, stream>>>(h0tmp, hpad);
  reduce_mean_v2<<<dim3(8, B_), 256, 0, stream>>>(hpad, invlens, g, gcur);
  fill_zero<<<(B_ * L_ * H_ + 255) / 256, 256, 0, stream>>>(cb0, B_ * L_ * H_);
  fill_zero<<<(B_ * H_ + 255) / 256, 256, 0, stream>>>(cgb0, B_ * H_);

  float* cb[2] = {cb0, cb1};
  float* cgb[2] = {cgb0, cgb1};
  int cur = 0;
  for (int step = 0; step < NSTEP; ++step) {
    int nxt = cur ^ 1;
    build_gates_A<<<(B_ * L_ * KG / 8 + 255) / 256, 256, 0, stream>>>(
        hpad, gcur, Ag);
    gemm_mfma<true><<<dim3(G7 / 128, (B_ * L_) / 128), 256, 0, stream>>>(
        Ag, Wgt, nullptr, xg, nullptr, gatesb, G7, KG, 0);
    cell_update_v2<<<(B_ * L_ * H_ + 255) / 256, 256, 0, stream>>>(
        gatesb, cb[cur], cgb[cur], maskf, hpad, cb[nxt]);
    reduce_mean_v2<<<dim3(8, B_), 256, 0, stream>>>(hpad, invlens, havg,
                                                    nullptr);
    gnode_v2<<<dim3(8, B_, 2), 256, 0, stream>>>(g, havg, Wgf, bgf, Wgo, bgo,
                                                 fg, og);
    build_fi_A<<<(B_ * L_ * KFI / 8 + 255) / 256, 256, 0, stream>>>(hpad, gcur,
                                                                    Afi);
    gemm_mfma<false><<<dim3(H_ / 128, (B_ * L_) / 128), 256, 0, stream>>>(
        Afi, Wfit, bfi, nullptr, nullptr, fi, H_, KFI, 0);
    slot_update_v2<<<(B_ * H_) / 64, 256, 0, stream>>>(
        fg, fi, og, cb[nxt], cgb[cur], maskf, cgb[nxt], g, gcur);
    cur = nxt;
  }
  final1_kernel<<<(B_ * 2 * H_ + 255) / 256, 256, 0, stream>>>(g, W1, b1, t1);
  final2_kernel<<<1, 64, 0, stream>>>(t1, W2, b2, out);
}